// Round 1
// baseline (2258.128 us; speedup 1.0000x reference)
//
#include <hip/hip_runtime.h>

#define INF 1e8f

constexpr int N = 2048;   // rows (x)
constexpr int M = 2048;   // cols (y)
constexpr int K = 64;     // feature dim
constexpr int L = N + 1;  // diagonal buffer length (i = 0..N)

// ---------------------------------------------------------------------------
// Distance kernel: D[i,j] = ||x_i - y_j||^2, 32x32 tile per 256-thread block,
// 2x2 cells per thread, LDS-staged with +4 pad (stride 68) to break bank
// conflicts on the k-loop reads.
// DIAG==0: store anti-diagonal-major Dd[(i+j)*2048 + idx]  (coalesced DP reads)
// DIAG==1: store row-major D[i*M + j]
// ---------------------------------------------------------------------------
constexpr int SP = K + 4;  // padded LDS row stride (floats), keeps 16B alignment

template <int DIAG>
__device__ inline void store_cell(float* __restrict__ D, int ig, int jg, float v) {
    if constexpr (DIAG == 0) {
        int dd = ig + jg;                                // = d - 2
        int idx = (dd < M - 1) ? ig : (M - 1 - jg);      // i - ilo(d)
        D[(size_t)dd * 2048 + idx] = v;
    } else {
        D[(size_t)ig * M + jg] = v;
    }
}

template <int DIAG>
__global__ __launch_bounds__(256) void dist_kernel(const float* __restrict__ x,
                                                   const float* __restrict__ y,
                                                   float* __restrict__ D) {
    __shared__ float xs[32 * SP];
    __shared__ float ys[32 * SP];
    const int t  = threadIdx.x;
    const int i0 = blockIdx.y * 32;
    const int j0 = blockIdx.x * 32;

    // stage 32 rows x 64 floats of x and y (512 float4 each; 2 per thread)
    const float4* x4 = (const float4*)(x + (size_t)i0 * K);
    const float4* y4 = (const float4*)(y + (size_t)j0 * K);
#pragma unroll
    for (int idx = t; idx < 512; idx += 256) {
        int row = idx >> 4, col4 = idx & 15;
        *(float4*)&xs[row * SP + col4 * 4] = x4[idx];
        *(float4*)&ys[row * SP + col4 * 4] = y4[idx];
    }
    __syncthreads();

    const int ii = (t >> 4) << 1;  // 0,2,...,30
    const int jj = (t & 15) << 1;  // 0,2,...,30
    float a00 = 0.f, a01 = 0.f, a10 = 0.f, a11 = 0.f;
#pragma unroll
    for (int k = 0; k < K; k += 2) {
        float2 xa = *(const float2*)&xs[ii * SP + k];
        float2 xb = *(const float2*)&xs[(ii + 1) * SP + k];
        float2 ya = *(const float2*)&ys[jj * SP + k];
        float2 yb = *(const float2*)&ys[(jj + 1) * SP + k];
        float d;
        d = xa.x - ya.x; a00 += d * d;  d = xa.y - ya.y; a00 += d * d;
        d = xa.x - yb.x; a01 += d * d;  d = xa.y - yb.y; a01 += d * d;
        d = xb.x - ya.x; a10 += d * d;  d = xb.y - ya.y; a10 += d * d;
        d = xb.x - yb.x; a11 += d * d;  d = xb.y - yb.y; a11 += d * d;
    }
    const int gi = i0 + ii, gj = j0 + jj;
    store_cell<DIAG>(D, gi,     gj,     a00);
    store_cell<DIAG>(D, gi,     gj + 1, a01);
    store_cell<DIAG>(D, gi + 1, gj,     a10);
    store_cell<DIAG>(D, gi + 1, gj + 1, a11);
}

// ---------------------------------------------------------------------------
// DP kernel: single block, 1024 threads, anti-diagonal wavefront with
// triple-buffered diagonals in LDS. One __syncthreads per diagonal.
// MODE 0: D in diagonal-major layout (coalesced)
// MODE 1: D row-major
// MODE 2: fused — compute distance on the fly (ws too small fallback)
// ---------------------------------------------------------------------------
template <int MODE>
__global__ __launch_bounds__(1024) void dp_kernel(const float* __restrict__ Dmat,
                                                  const float* __restrict__ x,
                                                  const float* __restrict__ y,
                                                  float* __restrict__ out) {
    __shared__ float buf[3][L];  // 3 * 2049 * 4B = 24588 B
    const int tid = threadIdx.x;

    for (int i = tid; i < L; i += 1024) {
        buf[0][i] = (i == 0) ? 0.0f : INF;  // diagonal d=0: R[0,0]=0
        buf[1][i] = INF;                     // diagonal d=1: all INF
        buf[2][i] = INF;
    }
    __syncthreads();

    for (int d = 2; d <= N + M; ++d) {
        float*       __restrict__ curr = buf[d % 3];
        const float* __restrict__ p1   = buf[(d + 2) % 3];  // diagonal d-1
        const float* __restrict__ p2   = buf[(d + 1) % 3];  // diagonal d-2

        const int ilo = (d - M > 1) ? (d - M) : 1;
        const int ihi = (d - 1 < N) ? (d - 1) : N;
        const int w   = ihi - ilo + 1;

        for (int c = tid; c < w; c += 1024) {
            const int i = ilo + c;                  // row index
            const float a  = p2[i - 1];             // R[i-1, j-1]
            const float b  = p1[i - 1];             // R[i-1, j]
            const float cc = p1[i];                 // R[i,   j-1]
            const float m  = fminf(fminf(a, b), cc);
            const float s  = __expf(m - a) + __expf(m - b) + __expf(m - cc);
            const float sm = m - __logf(s);         // -log(e^-a + e^-b + e^-c)

            float dv;
            if constexpr (MODE == 0) {
                dv = Dmat[(size_t)(d - 2) * 2048 + c];
            } else if constexpr (MODE == 1) {
                dv = Dmat[(size_t)(i - 1) * M + (d - i - 1)];
            } else {
                const float* xr = x + (size_t)(i - 1) * K;
                const float* yr = y + (size_t)(d - i - 1) * K;
                float acc = 0.f;
#pragma unroll
                for (int k = 0; k < K; ++k) {
                    float df = xr[k] - yr[k];
                    acc += df * df;
                }
                dv = acc;
            }
            curr[i] = dv + sm;
        }
        if (tid == 0) curr[0] = INF;  // keep the boundary pinned (buf0 held 0.0)
        __syncthreads();
    }

    if (tid == 0) out[0] = buf[(N + M) % 3][N];  // R[N, M]
}

// ---------------------------------------------------------------------------
extern "C" void kernel_launch(void* const* d_in, const int* in_sizes, int n_in,
                              void* d_out, int out_size, void* d_ws, size_t ws_size,
                              hipStream_t stream) {
    (void)in_sizes; (void)n_in; (void)out_size;
    const float* x = (const float*)d_in[0];
    const float* y = (const float*)d_in[1];
    float* out = (float*)d_out;
    float* D   = (float*)d_ws;

    const size_t need_diag = (size_t)(N + M - 1) * 2048 * sizeof(float);  // 33.5 MB
    const size_t need_row  = (size_t)N * M * sizeof(float);               // 16.8 MB

    dim3 dgrid(M / 32, N / 32);
    if (ws_size >= need_diag) {
        dist_kernel<0><<<dgrid, 256, 0, stream>>>(x, y, D);
        dp_kernel<0><<<1, 1024, 0, stream>>>(D, x, y, out);
    } else if (ws_size >= need_row) {
        dist_kernel<1><<<dgrid, 256, 0, stream>>>(x, y, D);
        dp_kernel<1><<<1, 1024, 0, stream>>>(D, x, y, out);
    } else {
        dp_kernel<2><<<1, 1024, 0, stream>>>(nullptr, x, y, out);
    }
}